// Round 5
// baseline (357.561 us; speedup 1.0000x reference)
//
#include <hip/hip_runtime.h>
#include <hip/hip_bf16.h>
#include <cstdint>

// Problem constants (fixed by reference)
#define NN 100000
#define HH 96
#define AD 32
#define DE 16
#define EE 500000
#define NEG 0.01f

// Bucketing: 98 buckets of 1024 nodes per edge type
#define GSH 10
#define GSZ 1024
#define KB 98
#define CH 4096
#define BPT 123          // ceil(EE/CH)
#define PCAP 801056      // EE + 3*GSZ*KB  (padded record capacity per type)

typedef __bf16 bf16x8 __attribute__((ext_vector_type(8)));
typedef float  f32x4  __attribute__((ext_vector_type(4)));
typedef unsigned long long ull;
typedef unsigned long long ull2 __attribute__((ext_vector_type(2)));

__device__ __forceinline__ unsigned short f2b(float x) {
    union { float f; unsigned int u; } v; v.f = x;
    unsigned int r = v.u + 0x7fffu + ((v.u >> 16) & 1u);  // RNE
    return (unsigned short)(r >> 16);
}
__device__ __forceinline__ float b2f(unsigned short h) {
    union { unsigned int u; float f; } v; v.u = ((unsigned int)h) << 16;
    return v.f;
}

// ---------------------------------------------------------------------------
// prep: cvec[3][96], wvec[4][96], B-fragment-swizzled bf16 weights.
// Also zeroes bCnt (folded zero_kernel).
// BfN: 6 sections (S0,S1,S2,D0,D1,D2) x 3 ksteps x 6 colblocks x 64 lanes x 8
// BfU: 12 ksteps x 6 colblocks x 64 lanes x 8   (Wu 384x96)
// B-frag for mfma_f32_16x16x32_bf16: lane = ((k%32)/8)*16 + (n%16), j = k%8
// ---------------------------------------------------------------------------
__global__ void prep_kernel(const float* Wm0, const float* bm0, const float* ef0,
                            const float* Wm1, const float* bm1, const float* ef1,
                            const float* Wm2, const float* bm2, const float* ef2,
                            const float* Wn0, const float* Wa0,
                            const float* Wn1, const float* Wa1,
                            const float* Wu,
                            float* cvec, float* wvec,
                            unsigned short* BfN, unsigned short* BfU,
                            int* bCnt) {
    const float* Wm[3] = {Wm0, Wm1, Wm2};
    const float* bm[3] = {bm0, bm1, bm2};
    const float* ef[3] = {ef0, ef1, ef2};
    int tid0 = blockIdx.x * blockDim.x + threadIdx.x;
    if (tid0 < 3 * KB) bCnt[tid0] = 0;
    const int total = 288 + 384 + 55296 + 36864;
    for (int i = tid0; i < total; i += gridDim.x * blockDim.x) {
        if (i < 288) {
            int t = i / 96, j = i % 96;
            float s = bm[t][j];
            for (int k = 0; k < DE; ++k) s += ef[t][k] * Wm[t][(2 * HH + k) * HH + j];
            cvec[i] = s;
        } else if (i < 288 + 384) {
            int ii = i - 288;
            int kind = ii / 96, k = ii % 96;
            const float* Wn = (kind < 2) ? Wn0 : Wn1;
            const float* Wa = (kind < 2) ? Wa0 : Wa1;
            int off = (kind & 1) ? AD : 0;
            float s = 0.f;
            for (int a = 0; a < AD; ++a) s += Wn[k * AD + a] * Wa[off + a];
            wvec[ii] = s;
        } else if (i < 288 + 384 + 55296) {
            int ii = i - 672;
            int sec = ii / 9216; int rem = ii % 9216;
            int ksc = rem / 512; int lj = rem % 512;
            int ks = ksc / 6, c = ksc % 6;
            int lane = lj / 8, jj = lj % 8;
            int quad = lane / 16, m = lane % 16;
            int k = ks * 32 + quad * 8 + jj;
            int n = c * 16 + m;
            int mt = (sec < 3) ? sec : sec - 3;
            int rowoff = (sec < 3) ? 0 : HH;
            BfN[ii] = f2b(Wm[mt][(rowoff + k) * HH + n]);
        } else {
            int ii = i - (672 + 55296);
            int ksc = ii / 512; int lj = ii % 512;
            int ks = ksc / 6, c = ksc % 6;
            int lane = lj / 8, jj = lj % 8;
            int quad = lane / 16, m = lane % 16;
            int k = ks * 32 + quad * 8 + jj;
            int n = c * 16 + m;
            BfU[ii] = f2b(Wu[k * HH + n]);
        }
    }
}

// Fused: bf16 cast of h + u/v attention pre-dots. One 32-lane group per node.
__global__ void cast_uv_kernel(const float* __restrict__ h, const float* __restrict__ wvec,
                               unsigned short* __restrict__ hb, float* __restrict__ uv) {
    int lane = threadIdx.x & 31;
    int node = (blockIdx.x * blockDim.x + threadIdx.x) >> 5;
    if (node >= NN) return;
    float h0 = h[node * HH + lane];
    float h1 = h[node * HH + 32 + lane];
    float h2 = h[node * HH + 64 + lane];
    hb[node * HH + lane] = f2b(h0);
    hb[node * HH + 32 + lane] = f2b(h1);
    hb[node * HH + 64 + lane] = f2b(h2);
    float acc[4];
#pragma unroll
    for (int q = 0; q < 4; ++q)
        acc[q] = h0 * wvec[q * 96 + lane] + h1 * wvec[q * 96 + 32 + lane] +
                 h2 * wvec[q * 96 + 64 + lane];
#pragma unroll
    for (int d = 16; d >= 1; d >>= 1)
#pragma unroll
        for (int q = 0; q < 4; ++q) acc[q] += __shfl_down(acc[q], d, 32);
    if (lane == 0) {
#pragma unroll
        for (int q = 0; q < 4; ++q) uv[q * NN + node] = acc[q];
    }
}

// ---------------------------------------------------------------------------
// Two-level CSR build: bucket hist -> scan -> LDS-ranked scatter (u32 recs,
// line-dense writes) -> per-bucket counting sort. The sort pads each node's
// list to a multiple of 4 with zero-weight records (bucket slack 3*GSZ,
// padded bucket base = eb + 3072*b, no extra scan), computes the edge
// attention weight ONCE per edge (u[src] gather + v[dst] from LDS), and
// emits wrec = {w:f32 | src*192} plus per-node rse = {padded_cnt | start}.
// ---------------------------------------------------------------------------
__global__ void bucket_hist(const int* __restrict__ d0, const int* __restrict__ d1,
                            const int* __restrict__ d2, int* __restrict__ bCnt) {
    __shared__ int hist[3 * KB];
    int t = threadIdx.x;
    for (int j = t; j < 3 * KB; j += 256) hist[j] = 0;
    __syncthreads();
    const int total = 3 * EE;
    for (int i = blockIdx.x * blockDim.x + t; i < total; i += gridDim.x * blockDim.x) {
        int ty = i / EE, e = i - ty * EE;
        const int* d = (ty == 0) ? d0 : (ty == 1) ? d1 : d2;
        atomicAdd(&hist[ty * KB + (d[e] >> GSH)], 1);
    }
    __syncthreads();
    for (int j = t; j < 3 * KB; j += 256)
        if (hist[j]) atomicAdd(&bCnt[j], hist[j]);
}

__global__ void bucket_scan(const int* __restrict__ bCnt, int* __restrict__ bBase,
                            int* __restrict__ gCursor) {
    __shared__ int hist[3 * KB];
    int t = threadIdx.x;
    if (t < 3 * KB) hist[t] = bCnt[t];
    __syncthreads();
    if (t < 3) {
        int run = 0;
        for (int b = 0; b < KB; ++b) {
            bBase[t * (KB + 1) + b] = run;
            gCursor[t * KB + b] = run;
            run += hist[t * KB + b];
        }
        bBase[t * (KB + 1) + KB] = run;           // == EE
    }
}

__global__ __launch_bounds__(256) void bucket_scatter(
    const int* __restrict__ s0, const int* __restrict__ d0,
    const int* __restrict__ s1, const int* __restrict__ d1,
    const int* __restrict__ s2, const int* __restrict__ d2,
    int* __restrict__ gCursor, unsigned int* __restrict__ binned) {
    __shared__ unsigned int recs[CH];
    __shared__ unsigned short rnk[CH];
    __shared__ unsigned char bkt[CH];
    __shared__ int cnt[KB];
    __shared__ int gpos[KB];
    int t = threadIdx.x;
    int type = blockIdx.x / BPT;
    int chunk = (blockIdx.x % BPT) * CH;
    const int* src = (type == 0) ? s0 : (type == 1) ? s1 : s2;
    const int* dst = (type == 0) ? d0 : (type == 1) ? d1 : d2;
    if (t < KB) cnt[t] = 0;
    __syncthreads();
#pragma unroll
    for (int k = 0; k < CH / 256; ++k) {
        int idx = k * 256 + t;
        int e = chunk + idx;
        if (e < EE) {
            int s = src[e], d = dst[e];
            int b = d >> GSH;
            recs[idx] = ((unsigned int)s << GSH) | (unsigned int)(d & (GSZ - 1));
            bkt[idx] = (unsigned char)b;
            rnk[idx] = (unsigned short)atomicAdd(&cnt[b], 1);
        } else {
            bkt[idx] = 0xFF;
        }
    }
    __syncthreads();
    if (t < KB) {
        int c = cnt[t];
        gpos[t] = (c > 0) ? atomicAdd(&gCursor[type * KB + t], c) : 0;
    }
    __syncthreads();
    unsigned int* bout = binned + (size_t)type * EE;
#pragma unroll
    for (int k = 0; k < CH / 256; ++k) {
        int idx = k * 256 + t;
        unsigned char b = bkt[idx];
        if (b != 0xFF) bout[gpos[b] + rnk[idx]] = recs[idx];
    }
}

__global__ __launch_bounds__(256) void bucket_sort(
    const unsigned int* __restrict__ binned, const int* __restrict__ bBase,
    const float* __restrict__ uv,
    ull* __restrict__ rse, ull* __restrict__ wrec) {
    __shared__ int cnt[GSZ];
    __shared__ int tsum[256];
    __shared__ float vbuf[GSZ];
    int t = threadIdx.x;
    int type = blockIdx.x / KB;
    int b = blockIdx.x % KB;
    int nodeBase = b * GSZ;
    int eb = bBase[type * (KB + 1) + b];
    int en = bBase[type * (KB + 1) + b + 1];
    int n = en - eb;
    int pbase = eb + 3 * GSZ * b;   // padded bucket base (slack 3*GSZ/bucket)
    const unsigned int* bin = binned + (size_t)type * EE + eb;
#pragma unroll
    for (int k = 0; k < GSZ / 256; ++k) cnt[k * 256 + t] = 0;
    if (type < 2) {
        const float* vsrc = uv + (2 * type + 1) * NN;
#pragma unroll
        for (int k = 0; k < GSZ / 256; ++k) {
            int nd = nodeBase + k * 256 + t;
            vbuf[k * 256 + t] = (nd < NN) ? vsrc[nd] : 0.f;
        }
    }
    __syncthreads();
    for (int i = t; i < n; i += 256) atomicAdd(&cnt[bin[i] & (GSZ - 1)], 1);
    __syncthreads();
    int v[4], pv[4], s = 0;
#pragma unroll
    for (int k = 0; k < 4; ++k) {
        v[k] = cnt[t * 4 + k];
        pv[k] = (v[k] + 3) & ~3;
        s += pv[k];
    }
    tsum[t] = s;
    __syncthreads();
    for (int off = 1; off < 256; off <<= 1) {
        int add = (t >= off) ? tsum[t - off] : 0;
        __syncthreads();
        tsum[t] += add;
        __syncthreads();
    }
    int run = tsum[t] - s;  // exclusive padded base for this thread's 4 nodes
    int offk[4];
#pragma unroll
    for (int k = 0; k < 4; ++k) { offk[k] = run; run += pv[k]; }
    ull* wb = wrec + (size_t)type * PCAP;
#pragma unroll
    for (int k = 0; k < 4; ++k) {
        int node = nodeBase + t * 4 + k;
        if (node < NN) {
            rse[(size_t)type * NN + node] =
                ((ull)(unsigned int)pv[k] << 32) | (unsigned int)(pbase + offk[k]);
            for (int q = v[k]; q < pv[k]; ++q) wb[pbase + offk[k] + q] = 0ull;
        }
    }
    __syncthreads();  // all cnt reads done before overwrite
#pragma unroll
    for (int k = 0; k < 4; ++k) cnt[t * 4 + k] = offk[k];
    __syncthreads();
    const float* usrc = uv + 2 * type * NN;
    for (int i = t; i < n; i += 256) {
        unsigned int r = bin[i];
        int dl = r & (GSZ - 1);
        int p = atomicAdd(&cnt[dl], 1);
        unsigned int sidx = r >> GSH;
        float w = 1.f;
        if (type < 2) {
            float c = usrc[sidx] + vbuf[dl];
            c = fmaxf(c, NEG * c);  // leaky_relu
            w = __expf(c);
        }
        wb[pbase + p] = ((ull)__float_as_uint(w) << 32) | (ull)(sidx * 192u);
    }
}

// All-type h-space gather aggregation in ONE launch: grid (12500, 3).
// Linearity: (sum w*P[s])/W = ((sum w*h[s])/W) @ WmS, so gather h rows and
// defer the 96x96 GEMM to the fused GEMM. hagg_t[d] = (sum w_e h[src_e])/W.
// Lists are padded to x4 with zero-weight records: no conditionals in the
// loop, 32B-aligned record loads (group-uniform -> HW broadcast). Lane l
// owns columns {2l, 2l+1, 64+l}: one dword + one ushort load per edge.
__global__ void aggregate_kernel(const ull* __restrict__ rse,
                                 const ull* __restrict__ wrec,
                                 const unsigned short* __restrict__ hb,
                                 unsigned short* __restrict__ hagg,
                                 float* __restrict__ den) {
    const size_t NH = (size_t)NN * HH;
    int lane = threadIdx.x & 31;
    int node = (blockIdx.x * blockDim.x + threadIdx.x) >> 5;
    if (node >= NN) return;
    int t = blockIdx.y;
    ull se = rse[(size_t)t * NN + node];
    int beg = (int)(unsigned int)se;
    int end = beg + (int)(se >> 32);
    const ull* wr = wrec + (size_t)t * PCAP;
    float a0 = 0.f, a1 = 0.f, a2 = 0.f, dn = 0.f;
    const char* b0 = (const char*)hb + 4 * lane;        // cols 2l,2l+1 (dword)
    const char* b1 = (const char*)hb + 128 + 2 * lane;  // col 64+l (ushort)
#define EDGE(rec)                                                              \
    {                                                                          \
        float w = __uint_as_float((unsigned int)((rec) >> 32));                \
        unsigned int off = (unsigned int)(rec);                                \
        unsigned int dv = *(const unsigned int*)(b0 + off);                    \
        unsigned int sv = *(const unsigned short*)(b1 + off);                  \
        a0 += w * __uint_as_float(dv << 16);                                   \
        a1 += w * __uint_as_float(dv & 0xFFFF0000u);                           \
        a2 += w * __uint_as_float(sv << 16);                                   \
        dn += w;                                                               \
    }
    for (int j = beg; j < end; j += 4) {
        ull2 p0 = *(const ull2*)(wr + j);
        ull2 p1 = *(const ull2*)(wr + j + 2);
        EDGE(p0[0]);
        EDGE(p0[1]);
        EDGE(p1[0]);
        EDGE(p1[1]);
    }
#undef EDGE
    float inv = (dn > 0.f) ? 1.f / dn : 0.f;
    float q0 = a0 * inv, q1 = a1 * inv, q2 = a2 * inv;
    char* mr = (char*)(hagg + (size_t)t * NH + (size_t)node * HH);
    *(unsigned int*)(mr + 4 * lane) =
        (unsigned int)f2b(q0) | ((unsigned int)f2b(q1) << 16);
    *(unsigned short*)(mr + 128 + 2 * lane) = f2b(q2);
    if (lane == 0) den[(size_t)t * NN + node] = dn;
}

// Fused msg+update GEMM: one wave per 16-row tile, grid 1563 x 4 waves.
// For each t: m_t = z_t*(hagg_t@WmS_t + h@WmD_t + c_t) in acc regs (K=192),
// quantize bf16 (identical f2b path as the old msgb), round-trip through a
// wave-private LDS slab (row stride 208B -> <=2-way ds conflicts, no
// __syncthreads needed) to convert acc layout -> A-frag layout, then
// accO += m_t @ Wu_t. Finally out = relu(h@Wu_h + sum + bu).
// Kills the 115MB msgb HBM round-trip and 2 extra hb passes.
__global__ __launch_bounds__(256) void fused_gemm_kernel(
    const unsigned short* __restrict__ hagg,
    const unsigned short* __restrict__ hb,
    const unsigned short* __restrict__ BfN,
    const unsigned short* __restrict__ BfU,
    const float* __restrict__ den,
    const float* __restrict__ cvec,
    const float* __restrict__ bu,
    float* __restrict__ out) {
    const size_t NH = (size_t)NN * HH;
    __shared__ unsigned short lds[4][16][104];   // 104 shorts = 208B row stride
    int wave = threadIdx.x >> 6;
    int lane = threadIdx.x & 63;
    int quad = lane >> 4, m = lane & 15;
    int blk = blockIdx.x * 4 + wave;
    if (blk >= NN / 16) return;
    int r0 = blk * 16;
    unsigned short (*L)[104] = lds[wave];

    f32x4 accO[6] = {};
    // h part of the update GEMM: ksteps 0..2 of BfU
#pragma unroll
    for (int ks = 0; ks < 3; ++ks) {
        bf16x8 af = *(const bf16x8*)(hb + (size_t)(r0 + m) * HH + ks * 32 + quad * 8);
#pragma unroll
        for (int c = 0; c < 6; ++c) {
            bf16x8 bfv = *(const bf16x8*)(BfU + ((ks * 6 + c) << 9) + lane * 8);
            accO[c] = __builtin_amdgcn_mfma_f32_16x16x32_bf16(af, bfv, accO[c], 0, 0, 0);
        }
    }
#pragma unroll 1
    for (int t = 0; t < 3; ++t) {
        const unsigned short* ha = hagg + (size_t)t * NH;
        f32x4 acc[6] = {};
#pragma unroll
        for (int ks = 0; ks < 6; ++ks) {
            const unsigned short* ap =
                (ks < 3) ? ha + (size_t)(r0 + m) * HH + ks * 32 + quad * 8
                         : hb + (size_t)(r0 + m) * HH + (ks - 3) * 32 + quad * 8;
            int sec = (ks < 3) ? t : t + 3;
            int kk = (ks < 3) ? ks : ks - 3;
            bf16x8 af = *(const bf16x8*)ap;
#pragma unroll
            for (int c = 0; c < 6; ++c) {
                bf16x8 bfv = *(const bf16x8*)(BfN + (((sec * 3 + kk) * 6 + c) << 9) + lane * 8);
                acc[c] = __builtin_amdgcn_mfma_f32_16x16x32_bf16(af, bfv, acc[c], 0, 0, 0);
            }
        }
        float dn[4];
#pragma unroll
        for (int r = 0; r < 4; ++r) dn[r] = den[(size_t)t * NN + r0 + quad * 4 + r];
        // acc layout: col = c*16 + m, row = quad*4 + r -> LDS (bf16, msg quant)
#pragma unroll
        for (int c = 0; c < 6; ++c) {
            float cv = cvec[t * 96 + c * 16 + m];
#pragma unroll
            for (int r = 0; r < 4; ++r) {
                float val = (dn[r] > 0.f) ? (acc[c][r] + cv) : 0.f;
                L[quad * 4 + r][c * 16 + m] = f2b(val);
            }
        }
        // A-frag read back: lane (quad*16+m) holds row m, k = ks*32+quad*8..
        // (wave-private slab: ds ordering within the wave via lgkmcnt)
#pragma unroll
        for (int ks = 0; ks < 3; ++ks) {
            bf16x8 af = *(const bf16x8*)&L[m][ks * 32 + quad * 8];
            int ku = 3 + t * 3 + ks;
#pragma unroll
            for (int c = 0; c < 6; ++c) {
                bf16x8 bfv = *(const bf16x8*)(BfU + ((ku * 6 + c) << 9) + lane * 8);
                accO[c] = __builtin_amdgcn_mfma_f32_16x16x32_bf16(af, bfv, accO[c], 0, 0, 0);
            }
        }
    }
#pragma unroll
    for (int c = 0; c < 6; ++c) {
        float b = bu[c * 16 + m];
#pragma unroll
        for (int r = 0; r < 4; ++r) {
            int row = r0 + quad * 4 + r;
            float v2 = accO[c][r] + b;
            out[(size_t)row * HH + c * 16 + m] = v2 > 0.f ? v2 : 0.f;
        }
    }
}

extern "C" void kernel_launch(void* const* d_in, const int* in_sizes, int n_in,
                              void* d_out, int out_size, void* d_ws, size_t ws_size,
                              hipStream_t stream) {
    (void)in_sizes; (void)n_in; (void)out_size;
    const float* h   = (const float*)d_in[0];
    const int* srcs[3] = {(const int*)d_in[1], (const int*)d_in[3], (const int*)d_in[5]};
    const int* dsts[3] = {(const int*)d_in[2], (const int*)d_in[4], (const int*)d_in[6]};
    const float* Wm0 = (const float*)d_in[7];
    const float* bm0 = (const float*)d_in[8];
    const float* ef0 = (const float*)d_in[9];
    const float* Wm1 = (const float*)d_in[10];
    const float* bm1 = (const float*)d_in[11];
    const float* ef1 = (const float*)d_in[12];
    const float* Wm2 = (const float*)d_in[13];
    const float* bm2 = (const float*)d_in[14];
    const float* ef2 = (const float*)d_in[15];
    const float* Wn0 = (const float*)d_in[16];
    const float* Wa0 = (const float*)d_in[17];
    const float* Wn1 = (const float*)d_in[18];
    const float* Wa1 = (const float*)d_in[19];
    const float* Wu  = (const float*)d_in[20];
    const float* bu  = (const float*)d_in[21];
    float* out = (float*)d_out;

    // Workspace layout (total ~165 MB; ws_size measured 256 MiB)
    const size_t NEED = 165016320;
    if (ws_size < NEED) return;  // fail validation cleanly instead of faulting
    char* w = (char*)d_ws;
    unsigned short* hb      = (unsigned short*)(w + 57600000);     // N*96 bf16
    unsigned short* hagg    = (unsigned short*)(w + 76800000);     // 3*N*96 bf16
    float*          den     = (float*)(w + 134400000);             // 3*N f32
    float*          uv      = (float*)(w + 135600000);             // 4*N f32
    float*          cvec    = (float*)(w + 137200000);             // 288 f32
    float*          wvec    = (float*)(w + 137201280);             // 384 f32
    unsigned short* BfN     = (unsigned short*)(w + 137202816);    // 55296 bf16
    unsigned short* BfU     = (unsigned short*)(w + 137313408);    // 36864 bf16
    int*            bBase   = (int*)(w + 137387136);               // 3*(KB+1) int
    int*            gCursor = (int*)(w + 137388416);               // 3*KB int
    int*            bCnt    = (int*)(w + 137389696);               // 3*KB int
    ull*            rse     = (ull*)(w + 137390976);               // 3*N u64
    unsigned int*   binned  = (unsigned int*)(w + 139790976);      // 3*E u32
    ull*            wrec    = (ull*)(w + 145790976);               // 3*PCAP u64 (16B aligned)

    prep_kernel<<<128, 256, 0, stream>>>(Wm0, bm0, ef0, Wm1, bm1, ef1, Wm2, bm2, ef2,
                                         Wn0, Wa0, Wn1, Wa1, Wu, cvec, wvec, BfN, BfU,
                                         bCnt);
    cast_uv_kernel<<<12500, 256, 0, stream>>>(h, wvec, hb, uv);

    // CSR build for all 3 edge types (bucketed two-level sort; the sort pads
    // to x4, computes edge weights, and emits rse/wrec).
    bucket_hist<<<512, 256, 0, stream>>>(dsts[0], dsts[1], dsts[2], bCnt);
    bucket_scan<<<1, 384, 0, stream>>>(bCnt, bBase, gCursor);
    bucket_scatter<<<3 * BPT, 256, 0, stream>>>(srcs[0], dsts[0], srcs[1], dsts[1],
                                                srcs[2], dsts[2], gCursor, binned);
    bucket_sort<<<3 * KB, 256, 0, stream>>>(binned, bBase, uv, rse, wrec);

    aggregate_kernel<<<dim3(12500, 3), 256, 0, stream>>>(rse, wrec, hb, hagg, den);
    fused_gemm_kernel<<<1563, 256, 0, stream>>>(hagg, hb, BfN, BfU, den, cvec, bu, out);
}

// Round 6
// 336.053 us; speedup vs baseline: 1.0640x; 1.0640x over previous
//
#include <hip/hip_runtime.h>
#include <hip/hip_bf16.h>
#include <cstdint>

// Problem constants (fixed by reference)
#define NN 100000
#define HH 96
#define AD 32
#define DE 16
#define EE 500000
#define NEG 0.01f

// Bucketing: 98 buckets of 1024 nodes per edge type
#define GSH 10
#define GSZ 1024
#define KB 98
#define CH 4096
#define BPT 123          // ceil(EE/CH)
#define PCAP 801056      // EE + 3*GSZ*KB  (padded record capacity per type)

typedef __bf16 bf16x8 __attribute__((ext_vector_type(8)));
typedef float  f32x4  __attribute__((ext_vector_type(4)));
typedef unsigned long long ull;
typedef unsigned long long ull2 __attribute__((ext_vector_type(2)));

__device__ __forceinline__ unsigned short f2b(float x) {
    union { float f; unsigned int u; } v; v.f = x;
    unsigned int r = v.u + 0x7fffu + ((v.u >> 16) & 1u);  // RNE
    return (unsigned short)(r >> 16);
}
__device__ __forceinline__ float b2f(unsigned short h) {
    union { unsigned int u; float f; } v; v.u = ((unsigned int)h) << 16;
    return v.f;
}

// ---------------------------------------------------------------------------
// prep: cvec[3][96], wvec[4][96], B-fragment-swizzled bf16 weights.
// Also zeroes bCnt (folded zero_kernel).
// BfN: 6 sections (S0,S1,S2,D0,D1,D2) x 3 ksteps x 6 colblocks x 64 lanes x 8
// BfU: 12 ksteps x 6 colblocks x 64 lanes x 8   (Wu 384x96)
// B-frag for mfma_f32_16x16x32_bf16: lane = ((k%32)/8)*16 + (n%16), j = k%8
// ---------------------------------------------------------------------------
__global__ void prep_kernel(const float* Wm0, const float* bm0, const float* ef0,
                            const float* Wm1, const float* bm1, const float* ef1,
                            const float* Wm2, const float* bm2, const float* ef2,
                            const float* Wn0, const float* Wa0,
                            const float* Wn1, const float* Wa1,
                            const float* Wu,
                            float* cvec, float* wvec,
                            unsigned short* BfN, unsigned short* BfU,
                            int* bCnt) {
    const float* Wm[3] = {Wm0, Wm1, Wm2};
    const float* bm[3] = {bm0, bm1, bm2};
    const float* ef[3] = {ef0, ef1, ef2};
    int tid0 = blockIdx.x * blockDim.x + threadIdx.x;
    if (tid0 < 3 * KB) bCnt[tid0] = 0;
    const int total = 288 + 384 + 55296 + 36864;
    for (int i = tid0; i < total; i += gridDim.x * blockDim.x) {
        if (i < 288) {
            int t = i / 96, j = i % 96;
            float s = bm[t][j];
            for (int k = 0; k < DE; ++k) s += ef[t][k] * Wm[t][(2 * HH + k) * HH + j];
            cvec[i] = s;
        } else if (i < 288 + 384) {
            int ii = i - 288;
            int kind = ii / 96, k = ii % 96;
            const float* Wn = (kind < 2) ? Wn0 : Wn1;
            const float* Wa = (kind < 2) ? Wa0 : Wa1;
            int off = (kind & 1) ? AD : 0;
            float s = 0.f;
            for (int a = 0; a < AD; ++a) s += Wn[k * AD + a] * Wa[off + a];
            wvec[ii] = s;
        } else if (i < 288 + 384 + 55296) {
            int ii = i - 672;
            int sec = ii / 9216; int rem = ii % 9216;
            int ksc = rem / 512; int lj = rem % 512;
            int ks = ksc / 6, c = ksc % 6;
            int lane = lj / 8, jj = lj % 8;
            int quad = lane / 16, m = lane % 16;
            int k = ks * 32 + quad * 8 + jj;
            int n = c * 16 + m;
            int mt = (sec < 3) ? sec : sec - 3;
            int rowoff = (sec < 3) ? 0 : HH;
            BfN[ii] = f2b(Wm[mt][(rowoff + k) * HH + n]);
        } else {
            int ii = i - (672 + 55296);
            int ksc = ii / 512; int lj = ii % 512;
            int ks = ksc / 6, c = ksc % 6;
            int lane = lj / 8, jj = lj % 8;
            int quad = lane / 16, m = lane % 16;
            int k = ks * 32 + quad * 8 + jj;
            int n = c * 16 + m;
            BfU[ii] = f2b(Wu[k * HH + n]);
        }
    }
}

// Fused: bf16 cast of h + u/v attention pre-dots. One 32-lane group per node.
__global__ void cast_uv_kernel(const float* __restrict__ h, const float* __restrict__ wvec,
                               unsigned short* __restrict__ hb, float* __restrict__ uv) {
    int lane = threadIdx.x & 31;
    int node = (blockIdx.x * blockDim.x + threadIdx.x) >> 5;
    if (node >= NN) return;
    float h0 = h[node * HH + lane];
    float h1 = h[node * HH + 32 + lane];
    float h2 = h[node * HH + 64 + lane];
    hb[node * HH + lane] = f2b(h0);
    hb[node * HH + 32 + lane] = f2b(h1);
    hb[node * HH + 64 + lane] = f2b(h2);
    float acc[4];
#pragma unroll
    for (int q = 0; q < 4; ++q)
        acc[q] = h0 * wvec[q * 96 + lane] + h1 * wvec[q * 96 + 32 + lane] +
                 h2 * wvec[q * 96 + 64 + lane];
#pragma unroll
    for (int d = 16; d >= 1; d >>= 1)
#pragma unroll
        for (int q = 0; q < 4; ++q) acc[q] += __shfl_down(acc[q], d, 32);
    if (lane == 0) {
#pragma unroll
        for (int q = 0; q < 4; ++q) uv[q * NN + node] = acc[q];
    }
}

// ---------------------------------------------------------------------------
// Two-level CSR build: bucket hist -> scan -> LDS-ranked scatter (u32 recs,
// line-dense writes) -> per-bucket counting sort. The sort pads each node's
// list to a multiple of 4 with zero-weight records (bucket slack 3*GSZ,
// padded bucket base = eb + 3072*b, no extra scan), computes the edge
// attention weight ONCE per edge (u[src] gather + v[dst] from LDS), and
// emits wrec = {w:f32 | src*192} plus per-node rse = {padded_cnt | start}.
// ---------------------------------------------------------------------------
__global__ void bucket_hist(const int* __restrict__ d0, const int* __restrict__ d1,
                            const int* __restrict__ d2, int* __restrict__ bCnt) {
    __shared__ int hist[3 * KB];
    int t = threadIdx.x;
    for (int j = t; j < 3 * KB; j += 256) hist[j] = 0;
    __syncthreads();
    const int total = 3 * EE;
    for (int i = blockIdx.x * blockDim.x + t; i < total; i += gridDim.x * blockDim.x) {
        int ty = i / EE, e = i - ty * EE;
        const int* d = (ty == 0) ? d0 : (ty == 1) ? d1 : d2;
        atomicAdd(&hist[ty * KB + (d[e] >> GSH)], 1);
    }
    __syncthreads();
    for (int j = t; j < 3 * KB; j += 256)
        if (hist[j]) atomicAdd(&bCnt[j], hist[j]);
}

__global__ void bucket_scan(const int* __restrict__ bCnt, int* __restrict__ bBase,
                            int* __restrict__ gCursor) {
    __shared__ int hist[3 * KB];
    int t = threadIdx.x;
    if (t < 3 * KB) hist[t] = bCnt[t];
    __syncthreads();
    if (t < 3) {
        int run = 0;
        for (int b = 0; b < KB; ++b) {
            bBase[t * (KB + 1) + b] = run;
            gCursor[t * KB + b] = run;
            run += hist[t * KB + b];
        }
        bBase[t * (KB + 1) + KB] = run;           // == EE
    }
}

__global__ __launch_bounds__(256) void bucket_scatter(
    const int* __restrict__ s0, const int* __restrict__ d0,
    const int* __restrict__ s1, const int* __restrict__ d1,
    const int* __restrict__ s2, const int* __restrict__ d2,
    int* __restrict__ gCursor, unsigned int* __restrict__ binned) {
    __shared__ unsigned int recs[CH];
    __shared__ unsigned short rnk[CH];
    __shared__ unsigned char bkt[CH];
    __shared__ int cnt[KB];
    __shared__ int gpos[KB];
    int t = threadIdx.x;
    int type = blockIdx.x / BPT;
    int chunk = (blockIdx.x % BPT) * CH;
    const int* src = (type == 0) ? s0 : (type == 1) ? s1 : s2;
    const int* dst = (type == 0) ? d0 : (type == 1) ? d1 : d2;
    if (t < KB) cnt[t] = 0;
    __syncthreads();
#pragma unroll
    for (int k = 0; k < CH / 256; ++k) {
        int idx = k * 256 + t;
        int e = chunk + idx;
        if (e < EE) {
            int s = src[e], d = dst[e];
            int b = d >> GSH;
            recs[idx] = ((unsigned int)s << GSH) | (unsigned int)(d & (GSZ - 1));
            bkt[idx] = (unsigned char)b;
            rnk[idx] = (unsigned short)atomicAdd(&cnt[b], 1);
        } else {
            bkt[idx] = 0xFF;
        }
    }
    __syncthreads();
    if (t < KB) {
        int c = cnt[t];
        gpos[t] = (c > 0) ? atomicAdd(&gCursor[type * KB + t], c) : 0;
    }
    __syncthreads();
    unsigned int* bout = binned + (size_t)type * EE;
#pragma unroll
    for (int k = 0; k < CH / 256; ++k) {
        int idx = k * 256 + t;
        unsigned char b = bkt[idx];
        if (b != 0xFF) bout[gpos[b] + rnk[idx]] = recs[idx];
    }
}

__global__ __launch_bounds__(256) void bucket_sort(
    const unsigned int* __restrict__ binned, const int* __restrict__ bBase,
    const float* __restrict__ uv,
    ull* __restrict__ rse, ull* __restrict__ wrec) {
    __shared__ int cnt[GSZ];
    __shared__ int tsum[256];
    __shared__ float vbuf[GSZ];
    int t = threadIdx.x;
    int type = blockIdx.x / KB;
    int b = blockIdx.x % KB;
    int nodeBase = b * GSZ;
    int eb = bBase[type * (KB + 1) + b];
    int en = bBase[type * (KB + 1) + b + 1];
    int n = en - eb;
    int pbase = eb + 3 * GSZ * b;   // padded bucket base (slack 3*GSZ/bucket)
    const unsigned int* bin = binned + (size_t)type * EE + eb;
#pragma unroll
    for (int k = 0; k < GSZ / 256; ++k) cnt[k * 256 + t] = 0;
    if (type < 2) {
        const float* vsrc = uv + (2 * type + 1) * NN;
#pragma unroll
        for (int k = 0; k < GSZ / 256; ++k) {
            int nd = nodeBase + k * 256 + t;
            vbuf[k * 256 + t] = (nd < NN) ? vsrc[nd] : 0.f;
        }
    }
    __syncthreads();
    for (int i = t; i < n; i += 256) atomicAdd(&cnt[bin[i] & (GSZ - 1)], 1);
    __syncthreads();
    int v[4], pv[4], s = 0;
#pragma unroll
    for (int k = 0; k < 4; ++k) {
        v[k] = cnt[t * 4 + k];
        pv[k] = (v[k] + 3) & ~3;
        s += pv[k];
    }
    tsum[t] = s;
    __syncthreads();
    for (int off = 1; off < 256; off <<= 1) {
        int add = (t >= off) ? tsum[t - off] : 0;
        __syncthreads();
        tsum[t] += add;
        __syncthreads();
    }
    int run = tsum[t] - s;  // exclusive padded base for this thread's 4 nodes
    int offk[4];
#pragma unroll
    for (int k = 0; k < 4; ++k) { offk[k] = run; run += pv[k]; }
    ull* wb = wrec + (size_t)type * PCAP;
#pragma unroll
    for (int k = 0; k < 4; ++k) {
        int node = nodeBase + t * 4 + k;
        if (node < NN) {
            rse[(size_t)type * NN + node] =
                ((ull)(unsigned int)pv[k] << 32) | (unsigned int)(pbase + offk[k]);
            for (int q = v[k]; q < pv[k]; ++q) wb[pbase + offk[k] + q] = 0ull;
        }
    }
    __syncthreads();  // all cnt reads done before overwrite
#pragma unroll
    for (int k = 0; k < 4; ++k) cnt[t * 4 + k] = offk[k];
    __syncthreads();
    const float* usrc = uv + 2 * type * NN;
    for (int i = t; i < n; i += 256) {
        unsigned int r = bin[i];
        int dl = r & (GSZ - 1);
        int p = atomicAdd(&cnt[dl], 1);
        unsigned int sidx = r >> GSH;
        float w = 1.f;
        if (type < 2) {
            float c = usrc[sidx] + vbuf[dl];
            c = fmaxf(c, NEG * c);  // leaky_relu
            w = __expf(c);
        }
        wb[pbase + p] = ((ull)__float_as_uint(w) << 32) | (ull)(sidx * 192u);
    }
}

// ---------------------------------------------------------------------------
// Fused aggregate + msg GEMM. Grid (6250, 3) x 512 threads.
// Phase 1: 16x 32-lane groups run the aggregate inner loop for 16 consecutive
//   nodes, writing the bf16-quantized hagg tile into LDS (identical f2b path
//   as the old global hagg => identical numerics) + den into LDS. This kills
//   the 115MB hagg round-trip and the den round-trip entirely.
// Phase 2 (after one __syncthreads): waves 0..5 each compute one 16-col block
//   of msg_t = z_t*(hagg@WmS_t + h@WmD_t + c_t): 6 chained MFMAs, A-frags
//   from LDS (row stride 208B -> exactly 8 accesses/bank, the b128 minimum),
//   then write bf16 msgb. 18750 blocks keep the machine saturated; the MFMA
//   tail (~500 cyc) is hidden across blocks (unlike round-5's serial chain).
// ---------------------------------------------------------------------------
__global__ __launch_bounds__(512) void agg_msg_kernel(
    const ull* __restrict__ rse,
    const ull* __restrict__ wrec,
    const unsigned short* __restrict__ hb,
    const unsigned short* __restrict__ BfN,
    const float* __restrict__ cvec,
    unsigned short* __restrict__ msgb) {
    __shared__ unsigned short Lh[16][104];   // 208B row stride
    __shared__ float dnL[16];
    int t = blockIdx.y;
    int tid = threadIdx.x;
    int lane = tid & 31;
    int g = tid >> 5;                        // 0..15: node within tile
    int node = blockIdx.x * 16 + g;          // NN = 6250*16 exactly

    // ---- phase 1: aggregate (verified round-4 inner loop) ----
    ull se = rse[(size_t)t * NN + node];
    int beg = (int)(unsigned int)se;
    int end = beg + (int)(se >> 32);
    const ull* wr = wrec + (size_t)t * PCAP;
    float a0 = 0.f, a1 = 0.f, a2 = 0.f, dn = 0.f;
    const char* b0 = (const char*)hb + 4 * lane;        // cols 2l,2l+1 (dword)
    const char* b1 = (const char*)hb + 128 + 2 * lane;  // col 64+l (ushort)
#define EDGE(rec)                                                              \
    {                                                                          \
        float w = __uint_as_float((unsigned int)((rec) >> 32));                \
        unsigned int off = (unsigned int)(rec);                                \
        unsigned int dv = *(const unsigned int*)(b0 + off);                    \
        unsigned int sv = *(const unsigned short*)(b1 + off);                  \
        a0 += w * __uint_as_float(dv << 16);                                   \
        a1 += w * __uint_as_float(dv & 0xFFFF0000u);                           \
        a2 += w * __uint_as_float(sv << 16);                                   \
        dn += w;                                                               \
    }
    for (int j = beg; j < end; j += 4) {
        ull2 p0 = *(const ull2*)(wr + j);
        ull2 p1 = *(const ull2*)(wr + j + 2);
        EDGE(p0[0]);
        EDGE(p0[1]);
        EDGE(p1[0]);
        EDGE(p1[1]);
    }
#undef EDGE
    float inv = (dn > 0.f) ? 1.f / dn : 0.f;
    float q0 = a0 * inv, q1 = a1 * inv, q2 = a2 * inv;
    char* mr = (char*)&Lh[g][0];
    *(unsigned int*)(mr + 4 * lane) =
        (unsigned int)f2b(q0) | ((unsigned int)f2b(q1) << 16);
    *(unsigned short*)(mr + 128 + 2 * lane) = f2b(q2);
    if (lane == 0) dnL[g] = dn;
    __syncthreads();

    // ---- phase 2: msg GEMM, one colblock per wave (waves 0..5) ----
    int wave = tid >> 6;
    if (wave >= 6) return;
    int l64 = tid & 63;
    int quad = l64 >> 4, m = l64 & 15;
    int c = wave;
    int r0 = blockIdx.x * 16;
    f32x4 acc = {};
#pragma unroll
    for (int ks = 0; ks < 6; ++ks) {
        bf16x8 af;
        if (ks < 3)
            af = *(const bf16x8*)((const char*)&Lh[m][0] + ks * 64 + quad * 16);
        else
            af = *(const bf16x8*)(hb + (size_t)(r0 + m) * HH + (ks - 3) * 32 + quad * 8);
        int sec = (ks < 3) ? t : t + 3;
        int kk = (ks < 3) ? ks : ks - 3;
        bf16x8 bfv = *(const bf16x8*)(BfN + (((sec * 3 + kk) * 6 + c) << 9) + l64 * 8);
        acc = __builtin_amdgcn_mfma_f32_16x16x32_bf16(af, bfv, acc, 0, 0, 0);
    }
    float cv = cvec[t * 96 + c * 16 + m];
#pragma unroll
    for (int r = 0; r < 4; ++r) {
        int row = r0 + quad * 4 + r;
        float dnv = dnL[quad * 4 + r];
        float val = (dnv > 0.f) ? (acc[r] + cv) : 0.f;
        msgb[(size_t)row * 288 + t * 96 + c * 16 + m] = f2b(val);
    }
}

// out = relu([h | msg] @ Wu + bu): M=100000, K=384, N=96
__global__ __launch_bounds__(256) void update_gemm_kernel(const unsigned short* __restrict__ hb,
                                                          const unsigned short* __restrict__ msgb,
                                                          const unsigned short* __restrict__ BfU,
                                                          const float* __restrict__ bu,
                                                          float* __restrict__ out) {
    int wave = threadIdx.x >> 6;
    int lane = threadIdx.x & 63;
    int quad = lane >> 4, m = lane & 15;
    int blk = blockIdx.x * 4 + wave;
    if (blk >= NN / 16) return;
    int r0 = blk * 16;
    f32x4 acc[6] = {};
#pragma unroll
    for (int ks = 0; ks < 12; ++ks) {
        const unsigned short* ap =
            (ks < 3) ? hb + (size_t)(r0 + m) * HH + ks * 32 + quad * 8
                     : msgb + (size_t)(r0 + m) * 288 + (ks - 3) * 32 + quad * 8;
        bf16x8 af = *(const bf16x8*)ap;
#pragma unroll
        for (int c = 0; c < 6; ++c) {
            bf16x8 bfv = *(const bf16x8*)(BfU + ((ks * 6 + c) << 9) + lane * 8);
            acc[c] = __builtin_amdgcn_mfma_f32_16x16x32_bf16(af, bfv, acc[c], 0, 0, 0);
        }
    }
#pragma unroll
    for (int c = 0; c < 6; ++c) {
        float b = bu[c * 16 + m];
#pragma unroll
        for (int r = 0; r < 4; ++r) {
            int row = r0 + quad * 4 + r;
            float v2 = acc[c][r] + b;
            out[(size_t)row * HH + c * 16 + m] = v2 > 0.f ? v2 : 0.f;
        }
    }
}

extern "C" void kernel_launch(void* const* d_in, const int* in_sizes, int n_in,
                              void* d_out, int out_size, void* d_ws, size_t ws_size,
                              hipStream_t stream) {
    (void)in_sizes; (void)n_in; (void)out_size;
    const float* h   = (const float*)d_in[0];
    const int* srcs[3] = {(const int*)d_in[1], (const int*)d_in[3], (const int*)d_in[5]};
    const int* dsts[3] = {(const int*)d_in[2], (const int*)d_in[4], (const int*)d_in[6]};
    const float* Wm0 = (const float*)d_in[7];
    const float* bm0 = (const float*)d_in[8];
    const float* ef0 = (const float*)d_in[9];
    const float* Wm1 = (const float*)d_in[10];
    const float* bm1 = (const float*)d_in[11];
    const float* ef1 = (const float*)d_in[12];
    const float* Wm2 = (const float*)d_in[13];
    const float* bm2 = (const float*)d_in[14];
    const float* ef2 = (const float*)d_in[15];
    const float* Wn0 = (const float*)d_in[16];
    const float* Wa0 = (const float*)d_in[17];
    const float* Wn1 = (const float*)d_in[18];
    const float* Wa1 = (const float*)d_in[19];
    const float* Wu  = (const float*)d_in[20];
    const float* bu  = (const float*)d_in[21];
    float* out = (float*)d_out;

    // Workspace layout (total ~165 MB; ws_size measured 256 MiB)
    const size_t NEED = 165016320;
    if (ws_size < NEED) return;  // fail validation cleanly instead of faulting
    char* w = (char*)d_ws;
    unsigned short* msgb    = (unsigned short*)(w + 0);            // N*288 bf16
    unsigned short* hb      = (unsigned short*)(w + 57600000);     // N*96 bf16
    float*          uv      = (float*)(w + 135600000);             // 4*N f32
    float*          cvec    = (float*)(w + 137200000);             // 288 f32
    float*          wvec    = (float*)(w + 137201280);             // 384 f32
    unsigned short* BfN     = (unsigned short*)(w + 137202816);    // 55296 bf16
    unsigned short* BfU     = (unsigned short*)(w + 137313408);    // 36864 bf16
    int*            bBase   = (int*)(w + 137387136);               // 3*(KB+1) int
    int*            gCursor = (int*)(w + 137388416);               // 3*KB int
    int*            bCnt    = (int*)(w + 137389696);               // 3*KB int
    ull*            rse     = (ull*)(w + 137390976);               // 3*N u64
    unsigned int*   binned  = (unsigned int*)(w + 139790976);      // 3*E u32
    ull*            wrec    = (ull*)(w + 145790976);               // 3*PCAP u64 (16B aligned)

    prep_kernel<<<128, 256, 0, stream>>>(Wm0, bm0, ef0, Wm1, bm1, ef1, Wm2, bm2, ef2,
                                         Wn0, Wa0, Wn1, Wa1, Wu, cvec, wvec, BfN, BfU,
                                         bCnt);
    cast_uv_kernel<<<12500, 256, 0, stream>>>(h, wvec, hb, uv);

    // CSR build for all 3 edge types (bucketed two-level sort; the sort pads
    // to x4, computes edge weights, and emits rse/wrec).
    bucket_hist<<<512, 256, 0, stream>>>(dsts[0], dsts[1], dsts[2], bCnt);
    bucket_scan<<<1, 384, 0, stream>>>(bCnt, bBase, gCursor);
    bucket_scatter<<<3 * BPT, 256, 0, stream>>>(srcs[0], dsts[0], srcs[1], dsts[1],
                                                srcs[2], dsts[2], gCursor, binned);
    bucket_sort<<<3 * KB, 256, 0, stream>>>(binned, bBase, uv, rse, wrec);

    agg_msg_kernel<<<dim3(6250, 3), 512, 0, stream>>>(rse, wrec, hb, BfN, cvec, msgb);
    update_gemm_kernel<<<1563, 256, 0, stream>>>(hb, msgb, BfU, bu, out);
}

// Round 8
// 328.857 us; speedup vs baseline: 1.0873x; 1.0219x over previous
//
#include <hip/hip_runtime.h>
#include <hip/hip_bf16.h>
#include <cstdint>

// Problem constants (fixed by reference)
#define NN 100000
#define HH 96
#define AD 32
#define DE 16
#define EE 500000
#define NEG 0.01f

// Bucketing: 196 buckets of 512 nodes per edge type
#define GSH 9
#define GSZ 512
#define KB 196
#define CH 2048
#define BPT 245          // ceil(EE/CH)
#define PCAP 801056      // EE + 3*GSZ*KB  (padded record capacity per type)

typedef __bf16 bf16x8 __attribute__((ext_vector_type(8)));
typedef float  f32x4  __attribute__((ext_vector_type(4)));
typedef unsigned long long ull;
typedef unsigned long long ull2 __attribute__((ext_vector_type(2)));

__device__ __forceinline__ unsigned short f2b(float x) {
    union { float f; unsigned int u; } v; v.f = x;
    unsigned int r = v.u + 0x7fffu + ((v.u >> 16) & 1u);  // RNE
    return (unsigned short)(r >> 16);
}
__device__ __forceinline__ float b2f(unsigned short h) {
    union { unsigned int u; float f; } v; v.u = ((unsigned int)h) << 16;
    return v.f;
}

// ---------------------------------------------------------------------------
// prep: cvec[3][96], wvec[4][96], B-fragment-swizzled bf16 weights.
// Also zeroes bCnt (folded zero_kernel).
// BfN: 6 sections (S0,S1,S2,D0,D1,D2) x 3 ksteps x 6 colblocks x 64 lanes x 8
// BfU: 12 ksteps x 6 colblocks x 64 lanes x 8   (Wu 384x96)
// B-frag for mfma_f32_16x16x32_bf16: lane = ((k%32)/8)*16 + (n%16), j = k%8
// ---------------------------------------------------------------------------
__global__ void prep_kernel(const float* Wm0, const float* bm0, const float* ef0,
                            const float* Wm1, const float* bm1, const float* ef1,
                            const float* Wm2, const float* bm2, const float* ef2,
                            const float* Wn0, const float* Wa0,
                            const float* Wn1, const float* Wa1,
                            const float* Wu,
                            float* cvec, float* wvec,
                            unsigned short* BfN, unsigned short* BfU,
                            int* bCnt) {
    const float* Wm[3] = {Wm0, Wm1, Wm2};
    const float* bm[3] = {bm0, bm1, bm2};
    const float* ef[3] = {ef0, ef1, ef2};
    int tid0 = blockIdx.x * blockDim.x + threadIdx.x;
    if (tid0 < 3 * KB) bCnt[tid0] = 0;
    const int total = 288 + 384 + 55296 + 36864;
    for (int i = tid0; i < total; i += gridDim.x * blockDim.x) {
        if (i < 288) {
            int t = i / 96, j = i % 96;
            float s = bm[t][j];
            for (int k = 0; k < DE; ++k) s += ef[t][k] * Wm[t][(2 * HH + k) * HH + j];
            cvec[i] = s;
        } else if (i < 288 + 384) {
            int ii = i - 288;
            int kind = ii / 96, k = ii % 96;
            const float* Wn = (kind < 2) ? Wn0 : Wn1;
            const float* Wa = (kind < 2) ? Wa0 : Wa1;
            int off = (kind & 1) ? AD : 0;
            float s = 0.f;
            for (int a = 0; a < AD; ++a) s += Wn[k * AD + a] * Wa[off + a];
            wvec[ii] = s;
        } else if (i < 288 + 384 + 55296) {
            int ii = i - 672;
            int sec = ii / 9216; int rem = ii % 9216;
            int ksc = rem / 512; int lj = rem % 512;
            int ks = ksc / 6, c = ksc % 6;
            int lane = lj / 8, jj = lj % 8;
            int quad = lane / 16, m = lane % 16;
            int k = ks * 32 + quad * 8 + jj;
            int n = c * 16 + m;
            int mt = (sec < 3) ? sec : sec - 3;
            int rowoff = (sec < 3) ? 0 : HH;
            BfN[ii] = f2b(Wm[mt][(rowoff + k) * HH + n]);
        } else {
            int ii = i - (672 + 55296);
            int ksc = ii / 512; int lj = ii % 512;
            int ks = ksc / 6, c = ksc % 6;
            int lane = lj / 8, jj = lj % 8;
            int quad = lane / 16, m = lane % 16;
            int k = ks * 32 + quad * 8 + jj;
            int n = c * 16 + m;
            BfU[ii] = f2b(Wu[k * HH + n]);
        }
    }
}

// Fused: bf16 cast of h + u/v attention pre-dots. One 32-lane group per node.
__global__ void cast_uv_kernel(const float* __restrict__ h, const float* __restrict__ wvec,
                               unsigned short* __restrict__ hb, float* __restrict__ uv) {
    int lane = threadIdx.x & 31;
    int node = (blockIdx.x * blockDim.x + threadIdx.x) >> 5;
    if (node >= NN) return;
    float h0 = h[node * HH + lane];
    float h1 = h[node * HH + 32 + lane];
    float h2 = h[node * HH + 64 + lane];
    hb[node * HH + lane] = f2b(h0);
    hb[node * HH + 32 + lane] = f2b(h1);
    hb[node * HH + 64 + lane] = f2b(h2);
    float acc[4];
#pragma unroll
    for (int q = 0; q < 4; ++q)
        acc[q] = h0 * wvec[q * 96 + lane] + h1 * wvec[q * 96 + 32 + lane] +
                 h2 * wvec[q * 96 + 64 + lane];
#pragma unroll
    for (int d = 16; d >= 1; d >>= 1)
#pragma unroll
        for (int q = 0; q < 4; ++q) acc[q] += __shfl_down(acc[q], d, 32);
    if (lane == 0) {
#pragma unroll
        for (int q = 0; q < 4; ++q) uv[q * NN + node] = acc[q];
    }
}

// ---------------------------------------------------------------------------
// Two-level CSR build: bucket hist -> scan -> LDS-ranked scatter (u32 recs,
// line-dense writes) -> per-bucket counting sort. The sort pads each node's
// list to a multiple of 4 with zero-weight records (bucket slack 3*GSZ,
// padded bucket base = eb + 3*GSZ*b, no extra scan), computes the edge
// attention weight ONCE per edge (u[src] gather + v[dst] from LDS), and
// emits wrec = {w:f32 | src*192} plus per-node rse = {padded_cnt | start}.
// Round 8: GSZ 1024->512 and CH 4096->2048 double the block counts of the
// two latency-starved kernels (sort: 294->588 blocks, scatter: 369->735).
// (Round 7 had this but crashed on an overlapping workspace layout.)
// ---------------------------------------------------------------------------
__global__ void bucket_hist(const int* __restrict__ d0, const int* __restrict__ d1,
                            const int* __restrict__ d2, int* __restrict__ bCnt) {
    __shared__ int hist[3 * KB];
    int t = threadIdx.x;
    for (int j = t; j < 3 * KB; j += 256) hist[j] = 0;
    __syncthreads();
    const int total = 3 * EE;
    for (int i = blockIdx.x * blockDim.x + t; i < total; i += gridDim.x * blockDim.x) {
        int ty = i / EE, e = i - ty * EE;
        const int* d = (ty == 0) ? d0 : (ty == 1) ? d1 : d2;
        atomicAdd(&hist[ty * KB + (d[e] >> GSH)], 1);
    }
    __syncthreads();
    for (int j = t; j < 3 * KB; j += 256)
        if (hist[j]) atomicAdd(&bCnt[j], hist[j]);
}

__global__ void bucket_scan(const int* __restrict__ bCnt, int* __restrict__ bBase,
                            int* __restrict__ gCursor) {
    __shared__ int hist[3 * KB];
    int t = threadIdx.x;
    if (t < 3 * KB) hist[t] = bCnt[t];
    __syncthreads();
    if (t < 3) {
        int run = 0;
        for (int b = 0; b < KB; ++b) {
            bBase[t * (KB + 1) + b] = run;
            gCursor[t * KB + b] = run;
            run += hist[t * KB + b];
        }
        bBase[t * (KB + 1) + KB] = run;           // == EE
    }
}

__global__ __launch_bounds__(256) void bucket_scatter(
    const int* __restrict__ s0, const int* __restrict__ d0,
    const int* __restrict__ s1, const int* __restrict__ d1,
    const int* __restrict__ s2, const int* __restrict__ d2,
    int* __restrict__ gCursor, unsigned int* __restrict__ binned) {
    __shared__ unsigned int recs[CH];
    __shared__ unsigned short rnk[CH];
    __shared__ unsigned char bkt[CH];
    __shared__ int cnt[KB];
    __shared__ int gpos[KB];
    int t = threadIdx.x;
    int type = blockIdx.x / BPT;
    int chunk = (blockIdx.x % BPT) * CH;
    const int* src = (type == 0) ? s0 : (type == 1) ? s1 : s2;
    const int* dst = (type == 0) ? d0 : (type == 1) ? d1 : d2;
    if (t < KB) cnt[t] = 0;
    __syncthreads();
#pragma unroll
    for (int k = 0; k < CH / 256; ++k) {
        int idx = k * 256 + t;
        int e = chunk + idx;
        if (e < EE) {
            int s = src[e], d = dst[e];
            int b = d >> GSH;
            recs[idx] = ((unsigned int)s << GSH) | (unsigned int)(d & (GSZ - 1));
            bkt[idx] = (unsigned char)b;
            rnk[idx] = (unsigned short)atomicAdd(&cnt[b], 1);
        } else {
            bkt[idx] = 0xFF;
        }
    }
    __syncthreads();
    if (t < KB) {
        int c = cnt[t];
        gpos[t] = (c > 0) ? atomicAdd(&gCursor[type * KB + t], c) : 0;
    }
    __syncthreads();
    unsigned int* bout = binned + (size_t)type * EE;
#pragma unroll
    for (int k = 0; k < CH / 256; ++k) {
        int idx = k * 256 + t;
        unsigned char b = bkt[idx];
        if (b != 0xFF) bout[gpos[b] + rnk[idx]] = recs[idx];
    }
}

__global__ __launch_bounds__(256) void bucket_sort(
    const unsigned int* __restrict__ binned, const int* __restrict__ bBase,
    const float* __restrict__ uv,
    ull* __restrict__ rse, ull* __restrict__ wrec) {
    __shared__ int cnt[GSZ];
    __shared__ float vbuf[GSZ];
    __shared__ int wsum[4];
    int t = threadIdx.x;
    int type = blockIdx.x / KB;
    int b = blockIdx.x % KB;
    int nodeBase = b * GSZ;
    int eb = bBase[type * (KB + 1) + b];
    int en = bBase[type * (KB + 1) + b + 1];
    int n = en - eb;
    int pbase = eb + 3 * GSZ * b;   // padded bucket base (slack 3*GSZ/bucket)
    const unsigned int* bin = binned + (size_t)type * EE + eb;
    cnt[t] = 0;
    cnt[t + 256] = 0;
    if (type < 2) {
        const float* vsrc = uv + (2 * type + 1) * NN;
        int nd0 = nodeBase + t, nd1 = nodeBase + 256 + t;
        vbuf[t] = (nd0 < NN) ? vsrc[nd0] : 0.f;
        vbuf[t + 256] = (nd1 < NN) ? vsrc[nd1] : 0.f;
    }
    __syncthreads();
    for (int i = t; i < n; i += 256) atomicAdd(&cnt[bin[i] & (GSZ - 1)], 1);
    __syncthreads();
    // thread t owns nodes 2t and 2t+1 of this bucket
    int v0 = cnt[t * 2], v1 = cnt[t * 2 + 1];
    int p0 = (v0 + 3) & ~3, p1 = (v1 + 3) & ~3;
    int s = p0 + p1;
    // wave-shuffle inclusive scan over 256 threads (1 barrier, not 16)
    int lane = t & 63, wv = t >> 6;
    int val = s;
#pragma unroll
    for (int d = 1; d < 64; d <<= 1) {
        int o = __shfl_up(val, d, 64);
        if (lane >= d) val += o;
    }
    if (lane == 63) wsum[wv] = val;
    __syncthreads();
    int wpre = 0;
#pragma unroll
    for (int i = 0; i < 4; ++i) wpre += (i < wv) ? wsum[i] : 0;
    int excl = val - s + wpre;   // exclusive padded base among this bucket's nodes
    int off0 = excl, off1 = excl + p0;
    ull* wb = wrec + (size_t)type * PCAP;
    int node0 = nodeBase + t * 2, node1 = nodeBase + t * 2 + 1;
    if (node0 < NN) {
        rse[(size_t)type * NN + node0] =
            ((ull)(unsigned int)p0 << 32) | (unsigned int)(pbase + off0);
        for (int q = v0; q < p0; ++q) wb[pbase + off0 + q] = 0ull;
    }
    if (node1 < NN) {
        rse[(size_t)type * NN + node1] =
            ((ull)(unsigned int)p1 << 32) | (unsigned int)(pbase + off1);
        for (int q = v1; q < p1; ++q) wb[pbase + off1 + q] = 0ull;
    }
    __syncthreads();  // all cnt reads done before overwrite
    cnt[t * 2] = off0;
    cnt[t * 2 + 1] = off1;
    __syncthreads();
    const float* usrc = uv + 2 * type * NN;
    for (int i = t; i < n; i += 256) {
        unsigned int r = bin[i];
        int dl = r & (GSZ - 1);
        int p = atomicAdd(&cnt[dl], 1);
        unsigned int sidx = r >> GSH;
        float w = 1.f;
        if (type < 2) {
            float c = usrc[sidx] + vbuf[dl];
            c = fmaxf(c, NEG * c);  // leaky_relu
            w = __expf(c);
        }
        wb[pbase + p] = ((ull)__float_as_uint(w) << 32) | (ull)(sidx * 192u);
    }
}

// All-type h-space gather aggregation in ONE launch: grid (12500, 3).
// Linearity: (sum w*P[s])/W = ((sum w*h[s])/W) @ WmS, so gather h rows and
// defer the 96x96 GEMM to msg_gemm. hagg_t[d] = (sum w_e h[src_e])/sum w_e.
// Lists are padded to x4 with zero-weight records: no conditionals in the
// loop, 32B-aligned record loads (group-uniform -> HW broadcast). Lane l
// owns columns {2l, 2l+1, 64+l}: one dword + one ushort load per edge.
__global__ void aggregate_kernel(const ull* __restrict__ rse,
                                 const ull* __restrict__ wrec,
                                 const unsigned short* __restrict__ hb,
                                 unsigned short* __restrict__ hagg,
                                 float* __restrict__ den) {
    const size_t NH = (size_t)NN * HH;
    int lane = threadIdx.x & 31;
    int node = (blockIdx.x * blockDim.x + threadIdx.x) >> 5;
    if (node >= NN) return;
    int t = blockIdx.y;
    ull se = rse[(size_t)t * NN + node];
    int beg = (int)(unsigned int)se;
    int end = beg + (int)(se >> 32);
    const ull* wr = wrec + (size_t)t * PCAP;
    float a0 = 0.f, a1 = 0.f, a2 = 0.f, dn = 0.f;
    const char* b0 = (const char*)hb + 4 * lane;        // cols 2l,2l+1 (dword)
    const char* b1 = (const char*)hb + 128 + 2 * lane;  // col 64+l (ushort)
#define EDGE(rec)                                                              \
    {                                                                          \
        float w = __uint_as_float((unsigned int)((rec) >> 32));                \
        unsigned int off = (unsigned int)(rec);                                \
        unsigned int dv = *(const unsigned int*)(b0 + off);                    \
        unsigned int sv = *(const unsigned short*)(b1 + off);                  \
        a0 += w * __uint_as_float(dv << 16);                                   \
        a1 += w * __uint_as_float(dv & 0xFFFF0000u);                           \
        a2 += w * __uint_as_float(sv << 16);                                   \
        dn += w;                                                               \
    }
    for (int j = beg; j < end; j += 4) {
        ull2 p0 = *(const ull2*)(wr + j);
        ull2 p1 = *(const ull2*)(wr + j + 2);
        EDGE(p0[0]);
        EDGE(p0[1]);
        EDGE(p1[0]);
        EDGE(p1[1]);
    }
#undef EDGE
    float inv = (dn > 0.f) ? 1.f / dn : 0.f;
    float q0 = a0 * inv, q1 = a1 * inv, q2 = a2 * inv;
    char* mr = (char*)(hagg + (size_t)t * NH + (size_t)node * HH);
    *(unsigned int*)(mr + 4 * lane) =
        (unsigned int)f2b(q0) | ((unsigned int)f2b(q1) << 16);
    *(unsigned short*)(mr + 128 + 2 * lane) = f2b(q2);
    if (lane == 0) den[(size_t)t * NN + node] = dn;
}

// msg_t = z_t * ( hagg_t @ WmS_t + h @ WmD_t + c_t ), K=192 MFMA, grid (1563,3).
// z_t = (den_t > 0) per row. Writes bf16 into msgb[:, t*96:(t+1)*96].
__global__ __launch_bounds__(256) void msg_gemm_kernel(const unsigned short* __restrict__ hagg,
                                                       const unsigned short* __restrict__ hb,
                                                       const unsigned short* __restrict__ BfN,
                                                       const float* __restrict__ den,
                                                       const float* __restrict__ cvec,
                                                       unsigned short* __restrict__ msgb) {
    const size_t NH = (size_t)NN * HH;
    int wave = threadIdx.x >> 6;
    int lane = threadIdx.x & 63;
    int quad = lane >> 4, m = lane & 15;
    int blk = blockIdx.x * 4 + wave;
    if (blk >= NN / 16) return;
    int t = blockIdx.y;
    int r0 = blk * 16;
    const unsigned short* ha = hagg + (size_t)t * NH;
    f32x4 acc[6] = {};
#pragma unroll
    for (int ks = 0; ks < 6; ++ks) {
        const unsigned short* ap =
            (ks < 3) ? ha + (size_t)(r0 + m) * HH + ks * 32 + quad * 8
                     : hb + (size_t)(r0 + m) * HH + (ks - 3) * 32 + quad * 8;
        int sec = (ks < 3) ? t : t + 3;
        int kk = (ks < 3) ? ks : ks - 3;
        bf16x8 af = *(const bf16x8*)ap;
#pragma unroll
        for (int c = 0; c < 6; ++c) {
            bf16x8 bfv = *(const bf16x8*)(BfN + (((sec * 3 + kk) * 6 + c) << 9) + lane * 8);
            acc[c] = __builtin_amdgcn_mfma_f32_16x16x32_bf16(af, bfv, acc[c], 0, 0, 0);
        }
    }
    float dn[4];
#pragma unroll
    for (int r = 0; r < 4; ++r) dn[r] = den[(size_t)t * NN + r0 + quad * 4 + r];
#pragma unroll
    for (int c = 0; c < 6; ++c) {
        float cv = cvec[t * 96 + c * 16 + m];
#pragma unroll
        for (int r = 0; r < 4; ++r) {
            int row = r0 + quad * 4 + r;
            float val = (dn[r] > 0.f) ? (acc[c][r] + cv) : 0.f;
            msgb[(size_t)row * 288 + t * 96 + c * 16 + m] = f2b(val);
        }
    }
}

// out = relu([h | msg] @ Wu + bu): M=100000, K=384, N=96
__global__ __launch_bounds__(256) void update_gemm_kernel(const unsigned short* __restrict__ hb,
                                                          const unsigned short* __restrict__ msgb,
                                                          const unsigned short* __restrict__ BfU,
                                                          const float* __restrict__ bu,
                                                          float* __restrict__ out) {
    int wave = threadIdx.x >> 6;
    int lane = threadIdx.x & 63;
    int quad = lane >> 4, m = lane & 15;
    int blk = blockIdx.x * 4 + wave;
    if (blk >= NN / 16) return;
    int r0 = blk * 16;
    f32x4 acc[6] = {};
#pragma unroll
    for (int ks = 0; ks < 12; ++ks) {
        const unsigned short* ap =
            (ks < 3) ? hb + (size_t)(r0 + m) * HH + ks * 32 + quad * 8
                     : msgb + (size_t)(r0 + m) * 288 + (ks - 3) * 32 + quad * 8;
        bf16x8 af = *(const bf16x8*)ap;
#pragma unroll
        for (int c = 0; c < 6; ++c) {
            bf16x8 bfv = *(const bf16x8*)(BfU + ((ks * 6 + c) << 9) + lane * 8);
            acc[c] = __builtin_amdgcn_mfma_f32_16x16x32_bf16(af, bfv, acc[c], 0, 0, 0);
        }
    }
#pragma unroll
    for (int c = 0; c < 6; ++c) {
        float b = bu[c * 16 + m];
#pragma unroll
        for (int r = 0; r < 4; ++r) {
            int row = r0 + quad * 4 + r;
            float v2 = acc[c][r] + b;
            out[(size_t)row * HH + c * 16 + m] = v2 > 0.f ? v2 : 0.f;
        }
    }
}

extern "C" void kernel_launch(void* const* d_in, const int* in_sizes, int n_in,
                              void* d_out, int out_size, void* d_ws, size_t ws_size,
                              hipStream_t stream) {
    (void)in_sizes; (void)n_in; (void)out_size;
    const float* h   = (const float*)d_in[0];
    const int* srcs[3] = {(const int*)d_in[1], (const int*)d_in[3], (const int*)d_in[5]};
    const int* dsts[3] = {(const int*)d_in[2], (const int*)d_in[4], (const int*)d_in[6]};
    const float* Wm0 = (const float*)d_in[7];
    const float* bm0 = (const float*)d_in[8];
    const float* ef0 = (const float*)d_in[9];
    const float* Wm1 = (const float*)d_in[10];
    const float* bm1 = (const float*)d_in[11];
    const float* ef1 = (const float*)d_in[12];
    const float* Wm2 = (const float*)d_in[13];
    const float* bm2 = (const float*)d_in[14];
    const float* ef2 = (const float*)d_in[15];
    const float* Wn0 = (const float*)d_in[16];
    const float* Wa0 = (const float*)d_in[17];
    const float* Wn1 = (const float*)d_in[18];
    const float* Wa1 = (const float*)d_in[19];
    const float* Wu  = (const float*)d_in[20];
    const float* bu  = (const float*)d_in[21];
    float* out = (float*)d_out;

    // Workspace layout (total ~165 MB; ws_size measured 256 MiB).
    // Control arrays each get their own padded 2432B slot (KB=196):
    //   bBase 3*(KB+1)*4 = 2364B, gCursor/bCnt 3*KB*4 = 2352B.
    const size_t NEED = 165019776;
    if (ws_size < NEED) return;  // fail validation cleanly instead of faulting
    char* w = (char*)d_ws;
    unsigned short* msgb    = (unsigned short*)(w + 0);            // N*288 bf16
    unsigned short* hb      = (unsigned short*)(w + 57600000);     // N*96 bf16
    unsigned short* hagg    = (unsigned short*)(w + 76800000);     // 3*N*96 bf16
    float*          den     = (float*)(w + 134400000);             // 3*N f32
    float*          uv      = (float*)(w + 135600000);             // 4*N f32
    float*          cvec    = (float*)(w + 137200000);             // 288 f32
    float*          wvec    = (float*)(w + 137201280);             // 384 f32
    unsigned short* BfN     = (unsigned short*)(w + 137202816);    // 55296 bf16
    unsigned short* BfU     = (unsigned short*)(w + 137313408);    // 36864 bf16
    int*            bBase   = (int*)(w + 137387136);               // [137387136, 137389568)
    int*            gCursor = (int*)(w + 137389568);               // [137389568, 137392000)
    int*            bCnt    = (int*)(w + 137392000);               // [137392000, 137394432)
    ull*            rse     = (ull*)(w + 137394432);               // 3*N u64 -> ends 139794432
    unsigned int*   binned  = (unsigned int*)(w + 139794432);      // 3*E u32 -> ends 145794432
    ull*            wrec    = (ull*)(w + 145794432);               // 3*PCAP u64 (16B aligned)

    prep_kernel<<<128, 256, 0, stream>>>(Wm0, bm0, ef0, Wm1, bm1, ef1, Wm2, bm2, ef2,
                                         Wn0, Wa0, Wn1, Wa1, Wu, cvec, wvec, BfN, BfU,
                                         bCnt);
    cast_uv_kernel<<<12500, 256, 0, stream>>>(h, wvec, hb, uv);

    // CSR build for all 3 edge types (bucketed two-level sort; the sort pads
    // to x4, computes edge weights, and emits rse/wrec).
    bucket_hist<<<512, 256, 0, stream>>>(dsts[0], dsts[1], dsts[2], bCnt);
    bucket_scan<<<1, 640, 0, stream>>>(bCnt, bBase, gCursor);
    bucket_scatter<<<3 * BPT, 256, 0, stream>>>(srcs[0], dsts[0], srcs[1], dsts[1],
                                                srcs[2], dsts[2], gCursor, binned);
    bucket_sort<<<3 * KB, 256, 0, stream>>>(binned, bBase, uv, rse, wrec);

    aggregate_kernel<<<dim3(12500, 3), 256, 0, stream>>>(rse, wrec, hb, hagg, den);
    msg_gemm_kernel<<<dim3(1563, 3), 256, 0, stream>>>(hagg, hb, BfN, den, cvec, msgb);
    update_gemm_kernel<<<1563, 256, 0, stream>>>(hb, msgb, BfU, bu, out);
}